// Round 1
// baseline (1128.722 us; speedup 1.0000x reference)
//
#include <hip/hip_runtime.h>

#define NN 100000
#define NE 1600000
#define HID 128
#define NG 512
#define MAXZ 1000

// ---------------- CSR build ----------------
__global__ __launch_bounds__(256) void hist_kernel(const int* __restrict__ dst, int e, int* __restrict__ deg) {
    int i = blockIdx.x * 256 + threadIdx.x;
    if (i < e) atomicAdd(&deg[dst[i]], 1);
}

__global__ __launch_bounds__(1024) void scan_kernel(const int* __restrict__ deg, int* __restrict__ off, int n) {
    __shared__ int buf[1024];
    int t = threadIdx.x;
    int carry = 0;
    for (int base = 0; base < n; base += 1024) {
        int i = base + t;
        int v = (i < n) ? deg[i] : 0;
        buf[t] = v;
        __syncthreads();
        for (int d = 1; d < 1024; d <<= 1) {
            int add = (t >= d) ? buf[t - d] : 0;
            __syncthreads();
            buf[t] += add;
            __syncthreads();
        }
        if (i < n) off[i] = carry + buf[t] - v;   // exclusive
        carry += buf[1023];
        __syncthreads();
    }
    if (t == 0) off[n] = carry;
}

__global__ __launch_bounds__(256) void scatter_kernel(const int* __restrict__ src, const int* __restrict__ dst,
                                                      int e, int* __restrict__ cursor, int* __restrict__ csr) {
    int i = blockIdx.x * 256 + threadIdx.x;
    if (i < e) {
        int d = dst[i];
        int pos = atomicAdd(&cursor[d], 1);
        csr[pos] = src[i];
    }
}

// ---------------- GEMM: Y[row,:] = Xsrc[row,:] @ W (+ addTab[addIdx[row],:]) ----------------
// Xsrc[row] = X[gatherIdx ? gatherIdx[row] : row], K = 128 fixed, 128 output cols.
#define FMA4(acc, s, w) { acc.x += (s)*(w).x; acc.y += (s)*(w).y; acc.z += (s)*(w).z; acc.w += (s)*(w).w; }

__global__ __launch_bounds__(256) void gemm128_kernel(
    const float* __restrict__ X, const float* __restrict__ W,
    float* __restrict__ Y, int nrows,
    const int* __restrict__ gatherIdx,
    const float* __restrict__ addTab, const int* __restrict__ addIdx)
{
    __shared__ float xs[32][132];   // [row][k], pad 132 keeps 16B alignment, no read conflicts
    int t = threadIdx.x;
    int row0 = blockIdx.x * 32;
    // stage 32 rows x 128 k, coalesced float4 per lane
    int sr = t >> 5;            // 0..7
    int sk = (t & 31) * 4;      // 0,4,...,124
#pragma unroll
    for (int p = 0; p < 4; ++p) {
        int r = p * 8 + sr;
        int grow = row0 + r;
        float4 v = make_float4(0.f, 0.f, 0.f, 0.f);
        if (grow < nrows) {
            long srcRow = gatherIdx ? (long)gatherIdx[grow] : (long)grow;
            v = *(const float4*)(X + srcRow * HID + sk);
        }
        *(float4*)(&xs[r][sk]) = v;
    }
    __syncthreads();

    int cg = t & 31, rg = t >> 5;
    int c = cg * 4;             // 4 output cols
    int r = rg * 4;             // 4 rows
    float4 a0 = make_float4(0,0,0,0), a1 = a0, a2 = a0, a3 = a0;
    for (int k = 0; k < 128; k += 4) {
        float x0[4], x1[4], x2[4], x3[4];
        *(float4*)x0 = *(const float4*)&xs[r + 0][k];
        *(float4*)x1 = *(const float4*)&xs[r + 1][k];
        *(float4*)x2 = *(const float4*)&xs[r + 2][k];
        *(float4*)x3 = *(const float4*)&xs[r + 3][k];
#pragma unroll
        for (int j = 0; j < 4; ++j) {
            float4 w = *(const float4*)(W + (k + j) * HID + c);
            FMA4(a0, x0[j], w);
            FMA4(a1, x1[j], w);
            FMA4(a2, x2[j], w);
            FMA4(a3, x3[j], w);
        }
    }

    float4 accs[4] = {a0, a1, a2, a3};
#pragma unroll
    for (int i = 0; i < 4; ++i) {
        int grow = row0 + r + i;
        if (grow < nrows) {
            float4 o = accs[i];
            if (addTab) {
                const float* ap = addTab + (long)addIdx[grow] * HID + c;
                o.x += ap[0]; o.y += ap[1]; o.z += ap[2]; o.w += ap[3];
            }
            *(float4*)(Y + (long)grow * HID + c) = o;
        }
    }
}

// ---------------- aggregate: Xo[i] = f(H[i] + sum_{j in CSR[i]} H[j] + bias) ----------------
__global__ __launch_bounds__(256) void aggregate_kernel(
    const float* __restrict__ H, float* __restrict__ Xo,
    const int* __restrict__ off, const int* __restrict__ csr,
    const float* __restrict__ bias, int n, int doRelu)
{
    int node = blockIdx.x * 4 + (threadIdx.x >> 6);   // one 64-lane wave per node
    if (node >= n) return;
    int lane = threadIdx.x & 63;
    int f = lane * 2;
    float2 acc = *(const float2*)(H + (long)node * HID + f);   // self (eps=0)
    int s = off[node], e = off[node + 1];
    for (int j = s; j < e; ++j) {
        int srcN = csr[j];
        float2 v = *(const float2*)(H + (long)srcN * HID + f);
        acc.x += v.x; acc.y += v.y;
    }
    float2 bb = *(const float2*)(bias + f);
    acc.x += bb.x; acc.y += bb.y;
    if (doRelu) { acc.x = fmaxf(acc.x, 0.f); acc.y = fmaxf(acc.y, 0.f); }
    *(float2*)(Xo + (long)node * HID + f) = acc;
}

// ---------------- pooling: per-graph mean (batch is sorted) ----------------
__global__ __launch_bounds__(128) void pool_kernel(const float* __restrict__ X, const int* __restrict__ batch,
                                                   int n, float* __restrict__ pooled) {
    int g = blockIdx.x;
    int t = threadIdx.x;   // feature
    int lo = 0, hi = n;
    while (lo < hi) { int m = (lo + hi) >> 1; if (batch[m] < g) lo = m + 1; else hi = m; }
    int s = lo;
    lo = 0; hi = n;
    while (lo < hi) { int m = (lo + hi) >> 1; if (batch[m] < g + 1) lo = m + 1; else hi = m; }
    int e = lo;
    float acc = 0.f;
    for (int i = s; i < e; ++i) acc += X[(long)i * HID + t];
    float cnt = (float)(e - s);
    pooled[g * HID + t] = acc / fmaxf(cnt, 1.f);
}

// ---------------- MLP head: Linear -> BN(eval, unit stats) -> ReLU -> Linear ----------------
__global__ __launch_bounds__(128) void mlp_kernel(
    const float* __restrict__ pooled, const float* __restrict__ W1, const float* __restrict__ b1,
    const float* __restrict__ gamma, const float* __restrict__ beta,
    const float* __restrict__ W2, const float* __restrict__ b2, float* __restrict__ out)
{
    int g = blockIdx.x, t = threadIdx.x;
    __shared__ float p[HID];
    __shared__ float red[4];
    p[t] = pooled[g * HID + t];
    __syncthreads();
    float acc = b1[t];
    for (int k = 0; k < HID; ++k) acc += p[k] * W1[k * HID + t];
    const float inv = 1.0f / sqrtf(1.0f + 1e-5f);
    acc = acc * (gamma[t] * inv) + beta[t];
    acc = fmaxf(acc, 0.f);
    float v0 = acc * W2[t * 2 + 0];
    float v1 = acc * W2[t * 2 + 1];
    for (int d = 32; d > 0; d >>= 1) { v0 += __shfl_down(v0, d); v1 += __shfl_down(v1, d); }
    int w = t >> 6, lane = t & 63;
    if (lane == 0) { red[w * 2] = v0; red[w * 2 + 1] = v1; }
    __syncthreads();
    if (t == 0) {
        out[g * 2 + 0] = red[0] + red[2] + b2[0];
        out[g * 2 + 1] = red[1] + red[3] + b2[1];
    }
}

extern "C" void kernel_launch(void* const* d_in, const int* in_sizes, int n_in,
                              void* d_out, int out_size, void* d_ws, size_t ws_size,
                              hipStream_t stream) {
    const int*   z        = (const int*)d_in[1];
    const int*   ei       = (const int*)d_in[2];
    const int*   batch    = (const int*)d_in[3];
    const int*   node_id  = (const int*)d_in[4];
    const float* z_emb    = (const float*)d_in[5];
    const float* node_emb = (const float*)d_in[6];
    const float* W0  = (const float*)d_in[7];
    const float* b0  = (const float*)d_in[8];
    const float* W1  = (const float*)d_in[9];
    const float* b1  = (const float*)d_in[10];
    const float* W2  = (const float*)d_in[11];
    const float* b2  = (const float*)d_in[12];
    const float* mW1 = (const float*)d_in[13];
    const float* mb1 = (const float*)d_in[14];
    const float* gam = (const float*)d_in[15];
    const float* bet = (const float*)d_in[16];
    const float* mW2 = (const float*)d_in[17];
    const float* mb2 = (const float*)d_in[18];
    float* out = (float*)d_out;

    const int* srcArr = ei;
    const int* dstArr = ei + NE;

    char* ws = (char*)d_ws;
    size_t o = 0;
    auto alloc = [&](size_t bytes) { char* p = ws + o; o += (bytes + 255) & ~(size_t)255; return p; };
    float* A      = (float*)alloc((size_t)NN * HID * 4);
    float* B      = (float*)alloc((size_t)NN * HID * 4);
    float* zW     = (float*)alloc((size_t)MAXZ * HID * 4);
    int*   deg    = (int*)alloc((size_t)NN * 4);
    int*   off    = (int*)alloc((size_t)(NN + 1) * 4);
    int*   cursor = (int*)alloc((size_t)NN * 4);
    int*   csr    = (int*)alloc((size_t)NE * 4);
    float* pooled = (float*)alloc((size_t)NG * HID * 4);
    (void)ws_size;

    // CSR by dst
    hipMemsetAsync(deg, 0, (size_t)NN * 4, stream);
    hist_kernel<<<(NE + 255) / 256, 256, 0, stream>>>(dstArr, NE, deg);
    scan_kernel<<<1, 1024, 0, stream>>>(deg, off, NN);
    hipMemcpyAsync(cursor, off, (size_t)NN * 4, hipMemcpyDeviceToDevice, stream);
    scatter_kernel<<<(NE + 255) / 256, 256, 0, stream>>>(srcArr, dstArr, NE, cursor, csr);

    // zW = z_emb @ W0[:128,:]   (tiny)
    gemm128_kernel<<<(MAXZ + 31) / 32, 256, 0, stream>>>(z_emb, W0, zW, MAXZ, nullptr, nullptr, nullptr);
    // B = node_emb[node_id] @ W0[128:,:] + zW[z]     (== x0 @ W0)
    gemm128_kernel<<<NN / 32, 256, 0, stream>>>(node_emb, W0 + 128 * HID, B, NN, node_id, zW, z);
    // layer 1 aggregate + b0 + relu
    aggregate_kernel<<<NN / 4, 256, 0, stream>>>(B, A, off, csr, b0, NN, 1);
    // layer 2
    gemm128_kernel<<<NN / 32, 256, 0, stream>>>(A, W1, B, NN, nullptr, nullptr, nullptr);
    aggregate_kernel<<<NN / 4, 256, 0, stream>>>(B, A, off, csr, b1, NN, 1);
    // layer 3 (no relu)
    gemm128_kernel<<<NN / 32, 256, 0, stream>>>(A, W2, B, NN, nullptr, nullptr, nullptr);
    aggregate_kernel<<<NN / 4, 256, 0, stream>>>(B, A, off, csr, b2, NN, 0);

    // global mean pool + MLP head
    pool_kernel<<<NG, 128, 0, stream>>>(A, batch, NN, pooled);
    mlp_kernel<<<NG, 128, 0, stream>>>(pooled, mW1, mb1, gam, bet, mW2, mb2, out);
}

// Round 2
// 968.871 us; speedup vs baseline: 1.1650x; 1.1650x over previous
//
#include <hip/hip_runtime.h>

#define NN 100000
#define NE 1600000
#define HID 128
#define NG 512
#define MAXZ 1000
#define SCAN_B 1024
#define NBLK ((NN + SCAN_B - 1) / SCAN_B)   // 98

// ---------------- CSR build ----------------
__global__ __launch_bounds__(256) void hist_kernel(const int* __restrict__ dst, int e, int* __restrict__ deg) {
    int i = blockIdx.x * 256 + threadIdx.x;
    if (i < e) atomicAdd(&deg[dst[i]], 1);
}

// phase 1: per-block exclusive scan + block partial
__global__ __launch_bounds__(1024) void scan_block_kernel(const int* __restrict__ deg, int* __restrict__ off,
                                                          int* __restrict__ part, int n) {
    __shared__ int buf[SCAN_B];
    int b = blockIdx.x, t = threadIdx.x;
    int i = b * SCAN_B + t;
    int v = (i < n) ? deg[i] : 0;
    buf[t] = v;
    __syncthreads();
    for (int d = 1; d < SCAN_B; d <<= 1) {
        int add = (t >= d) ? buf[t - d] : 0;
        __syncthreads();
        buf[t] += add;
        __syncthreads();
    }
    if (i < n) off[i] = buf[t] - v;       // exclusive within block
    if (t == SCAN_B - 1) part[b] = buf[SCAN_B - 1];
}

// phase 2: scan the (<=128) block partials, write grand total to off[n]
__global__ __launch_bounds__(128) void scan_part_kernel(int* __restrict__ part, int* __restrict__ off,
                                                        int nb, int n) {
    __shared__ int buf[128];
    int t = threadIdx.x;
    int v = (t < nb) ? part[t] : 0;
    buf[t] = v;
    __syncthreads();
    for (int d = 1; d < 128; d <<= 1) {
        int add = (t >= d) ? buf[t - d] : 0;
        __syncthreads();
        buf[t] += add;
        __syncthreads();
    }
    if (t < nb) part[t] = buf[t] - v;     // exclusive
    if (t == 127) off[n] = buf[127];      // total edge count
}

// phase 3: add block offset; also materialize cursor copy (replaces memcpy)
__global__ __launch_bounds__(1024) void scan_add_kernel(int* __restrict__ off, const int* __restrict__ part,
                                                        int* __restrict__ cursor, int n) {
    int b = blockIdx.x;
    int i = b * SCAN_B + threadIdx.x;
    if (i < n) {
        int v = off[i] + part[b];
        off[i] = v;
        cursor[i] = v;
    }
}

__global__ __launch_bounds__(256) void scatter_kernel(const int* __restrict__ src, const int* __restrict__ dst,
                                                      int e, int* __restrict__ cursor, int* __restrict__ csr) {
    int i = blockIdx.x * 256 + threadIdx.x;
    if (i < e) {
        int d = dst[i];
        int pos = atomicAdd(&cursor[d], 1);
        csr[pos] = src[i];
    }
}

// ---------------- GEMM: Y[row,:] = Xsrc[row,:] @ W (+ addTab[addIdx[row],:]) ----------------
#define FMA4(acc, s, w) { acc.x += (s)*(w).x; acc.y += (s)*(w).y; acc.z += (s)*(w).z; acc.w += (s)*(w).w; }

__global__ __launch_bounds__(256) void gemm128_kernel(
    const float* __restrict__ X, const float* __restrict__ W,
    float* __restrict__ Y, int nrows,
    const int* __restrict__ gatherIdx,
    const float* __restrict__ addTab, const int* __restrict__ addIdx)
{
    __shared__ float xs[32][132];
    int t = threadIdx.x;
    int row0 = blockIdx.x * 32;
    int sr = t >> 5;
    int sk = (t & 31) * 4;
#pragma unroll
    for (int p = 0; p < 4; ++p) {
        int r = p * 8 + sr;
        int grow = row0 + r;
        float4 v = make_float4(0.f, 0.f, 0.f, 0.f);
        if (grow < nrows) {
            long srcRow = gatherIdx ? (long)gatherIdx[grow] : (long)grow;
            v = *(const float4*)(X + srcRow * HID + sk);
        }
        *(float4*)(&xs[r][sk]) = v;
    }
    __syncthreads();

    int cg = t & 31, rg = t >> 5;
    int c = cg * 4;
    int r = rg * 4;
    float4 a0 = make_float4(0,0,0,0), a1 = a0, a2 = a0, a3 = a0;
    for (int k = 0; k < 128; k += 4) {
        float x0[4], x1[4], x2[4], x3[4];
        *(float4*)x0 = *(const float4*)&xs[r + 0][k];
        *(float4*)x1 = *(const float4*)&xs[r + 1][k];
        *(float4*)x2 = *(const float4*)&xs[r + 2][k];
        *(float4*)x3 = *(const float4*)&xs[r + 3][k];
#pragma unroll
        for (int j = 0; j < 4; ++j) {
            float4 w = *(const float4*)(W + (k + j) * HID + c);
            FMA4(a0, x0[j], w);
            FMA4(a1, x1[j], w);
            FMA4(a2, x2[j], w);
            FMA4(a3, x3[j], w);
        }
    }

    float4 accs[4] = {a0, a1, a2, a3};
#pragma unroll
    for (int i = 0; i < 4; ++i) {
        int grow = row0 + r + i;
        if (grow < nrows) {
            float4 o = accs[i];
            if (addTab) {
                const float* ap = addTab + (long)addIdx[grow] * HID + c;
                o.x += ap[0]; o.y += ap[1]; o.z += ap[2]; o.w += ap[3];
            }
            *(float4*)(Y + (long)grow * HID + c) = o;
        }
    }
}

// ---------------- aggregate: Xo[i] = f(H[i] + sum_{j in CSR[i]} H[j] + bias) ----------------
__global__ __launch_bounds__(256) void aggregate_kernel(
    const float* __restrict__ H, float* __restrict__ Xo,
    const int* __restrict__ off, const int* __restrict__ csr,
    const float* __restrict__ bias, int n, int doRelu)
{
    int node = blockIdx.x * 4 + (threadIdx.x >> 6);
    if (node >= n) return;
    int lane = threadIdx.x & 63;
    int f = lane * 2;
    float2 acc = *(const float2*)(H + (long)node * HID + f);
    int s = off[node], e = off[node + 1];
    for (int j = s; j < e; ++j) {
        int srcN = csr[j];
        float2 v = *(const float2*)(H + (long)srcN * HID + f);
        acc.x += v.x; acc.y += v.y;
    }
    float2 bb = *(const float2*)(bias + f);
    acc.x += bb.x; acc.y += bb.y;
    if (doRelu) { acc.x = fmaxf(acc.x, 0.f); acc.y = fmaxf(acc.y, 0.f); }
    *(float2*)(Xo + (long)node * HID + f) = acc;
}

// ---------------- pooling: per-graph mean (batch is sorted) ----------------
__global__ __launch_bounds__(128) void pool_kernel(const float* __restrict__ X, const int* __restrict__ batch,
                                                   int n, float* __restrict__ pooled) {
    int g = blockIdx.x;
    int t = threadIdx.x;
    int lo = 0, hi = n;
    while (lo < hi) { int m = (lo + hi) >> 1; if (batch[m] < g) lo = m + 1; else hi = m; }
    int s = lo;
    lo = 0; hi = n;
    while (lo < hi) { int m = (lo + hi) >> 1; if (batch[m] < g + 1) lo = m + 1; else hi = m; }
    int e = lo;
    float acc = 0.f;
    for (int i = s; i < e; ++i) acc += X[(long)i * HID + t];
    float cnt = (float)(e - s);
    pooled[g * HID + t] = acc / fmaxf(cnt, 1.f);
}

// ---------------- MLP head ----------------
__global__ __launch_bounds__(128) void mlp_kernel(
    const float* __restrict__ pooled, const float* __restrict__ W1, const float* __restrict__ b1,
    const float* __restrict__ gamma, const float* __restrict__ beta,
    const float* __restrict__ W2, const float* __restrict__ b2, float* __restrict__ out)
{
    int g = blockIdx.x, t = threadIdx.x;
    __shared__ float p[HID];
    __shared__ float red[4];
    p[t] = pooled[g * HID + t];
    __syncthreads();
    float acc = b1[t];
    for (int k = 0; k < HID; ++k) acc += p[k] * W1[k * HID + t];
    const float inv = 1.0f / sqrtf(1.0f + 1e-5f);
    acc = acc * (gamma[t] * inv) + beta[t];
    acc = fmaxf(acc, 0.f);
    float v0 = acc * W2[t * 2 + 0];
    float v1 = acc * W2[t * 2 + 1];
    for (int d = 32; d > 0; d >>= 1) { v0 += __shfl_down(v0, d); v1 += __shfl_down(v1, d); }
    int w = t >> 6, lane = t & 63;
    if (lane == 0) { red[w * 2] = v0; red[w * 2 + 1] = v1; }
    __syncthreads();
    if (t == 0) {
        out[g * 2 + 0] = red[0] + red[2] + b2[0];
        out[g * 2 + 1] = red[1] + red[3] + b2[1];
    }
}

extern "C" void kernel_launch(void* const* d_in, const int* in_sizes, int n_in,
                              void* d_out, int out_size, void* d_ws, size_t ws_size,
                              hipStream_t stream) {
    const int*   z        = (const int*)d_in[1];
    const int*   ei       = (const int*)d_in[2];
    const int*   batch    = (const int*)d_in[3];
    const int*   node_id  = (const int*)d_in[4];
    const float* z_emb    = (const float*)d_in[5];
    const float* node_emb = (const float*)d_in[6];
    const float* W0  = (const float*)d_in[7];
    const float* b0  = (const float*)d_in[8];
    const float* W1  = (const float*)d_in[9];
    const float* b1  = (const float*)d_in[10];
    const float* W2  = (const float*)d_in[11];
    const float* b2  = (const float*)d_in[12];
    const float* mW1 = (const float*)d_in[13];
    const float* mb1 = (const float*)d_in[14];
    const float* gam = (const float*)d_in[15];
    const float* bet = (const float*)d_in[16];
    const float* mW2 = (const float*)d_in[17];
    const float* mb2 = (const float*)d_in[18];
    float* out = (float*)d_out;

    const int* srcArr = ei;
    const int* dstArr = ei + NE;

    char* ws = (char*)d_ws;
    size_t o = 0;
    auto alloc = [&](size_t bytes) { char* p = ws + o; o += (bytes + 255) & ~(size_t)255; return p; };
    float* A      = (float*)alloc((size_t)NN * HID * 4);
    float* B      = (float*)alloc((size_t)NN * HID * 4);
    float* zW     = (float*)alloc((size_t)MAXZ * HID * 4);
    int*   deg    = (int*)alloc((size_t)NN * 4);
    int*   off    = (int*)alloc((size_t)(NN + 1) * 4);
    int*   cursor = (int*)alloc((size_t)NN * 4);
    int*   csr    = (int*)alloc((size_t)NE * 4);
    int*   part   = (int*)alloc((size_t)NBLK * 4);
    float* pooled = (float*)alloc((size_t)NG * HID * 4);
    (void)ws_size;

    // CSR by dst (multi-block scan)
    hipMemsetAsync(deg, 0, (size_t)NN * 4, stream);
    hist_kernel<<<(NE + 255) / 256, 256, 0, stream>>>(dstArr, NE, deg);
    scan_block_kernel<<<NBLK, SCAN_B, 0, stream>>>(deg, off, part, NN);
    scan_part_kernel<<<1, 128, 0, stream>>>(part, off, NBLK, NN);
    scan_add_kernel<<<NBLK, SCAN_B, 0, stream>>>(off, part, cursor, NN);
    scatter_kernel<<<(NE + 255) / 256, 256, 0, stream>>>(srcArr, dstArr, NE, cursor, csr);

    // zW = z_emb @ W0[:128,:]   (tiny)
    gemm128_kernel<<<(MAXZ + 31) / 32, 256, 0, stream>>>(z_emb, W0, zW, MAXZ, nullptr, nullptr, nullptr);
    // B = node_emb[node_id] @ W0[128:,:] + zW[z]     (== x0 @ W0)
    gemm128_kernel<<<NN / 32, 256, 0, stream>>>(node_emb, W0 + 128 * HID, B, NN, node_id, zW, z);
    aggregate_kernel<<<NN / 4, 256, 0, stream>>>(B, A, off, csr, b0, NN, 1);
    gemm128_kernel<<<NN / 32, 256, 0, stream>>>(A, W1, B, NN, nullptr, nullptr, nullptr);
    aggregate_kernel<<<NN / 4, 256, 0, stream>>>(B, A, off, csr, b1, NN, 1);
    gemm128_kernel<<<NN / 32, 256, 0, stream>>>(A, W2, B, NN, nullptr, nullptr, nullptr);
    aggregate_kernel<<<NN / 4, 256, 0, stream>>>(B, A, off, csr, b2, NN, 0);

    pool_kernel<<<NG, 128, 0, stream>>>(A, batch, NN, pooled);
    mlp_kernel<<<NG, 128, 0, stream>>>(pooled, mW1, mb1, gam, bet, mW2, mb2, out);
}

// Round 3
// 824.483 us; speedup vs baseline: 1.3690x; 1.1751x over previous
//
#include <hip/hip_runtime.h>

#define NN 100000
#define NE 1600000
#define HID 128
#define NG 512
#define MAXZ 1000
#define SCAN_B 1024
#define NBLK ((NN + SCAN_B - 1) / SCAN_B)   // 98

typedef unsigned short u16;
typedef unsigned int u32;
typedef __attribute__((ext_vector_type(8))) short bf16x8;
typedef __attribute__((ext_vector_type(4))) float f32x4;

__device__ __forceinline__ u16 bf16r(float x) {     // RNE f32->bf16
    u32 u = __float_as_uint(x);
    u32 r = (u + 0x7fffu + ((u >> 16) & 1u)) >> 16;
    return (u16)r;
}
__device__ __forceinline__ float bflo(u32 u) { return __uint_as_float(u << 16); }
__device__ __forceinline__ float bfhi(u32 u) { return __uint_as_float(u & 0xffff0000u); }

// ---------------- CSR build ----------------
__global__ __launch_bounds__(256) void hist_kernel(const int* __restrict__ dst, int e, int* __restrict__ deg) {
    int i = blockIdx.x * 256 + threadIdx.x;
    if (i < e) atomicAdd(&deg[dst[i]], 1);
}

__global__ __launch_bounds__(1024) void scan_block_kernel(const int* __restrict__ deg, int* __restrict__ off,
                                                          int* __restrict__ part, int n) {
    __shared__ int buf[SCAN_B];
    int b = blockIdx.x, t = threadIdx.x;
    int i = b * SCAN_B + t;
    int v = (i < n) ? deg[i] : 0;
    buf[t] = v;
    __syncthreads();
    for (int d = 1; d < SCAN_B; d <<= 1) {
        int add = (t >= d) ? buf[t - d] : 0;
        __syncthreads();
        buf[t] += add;
        __syncthreads();
    }
    if (i < n) off[i] = buf[t] - v;
    if (t == SCAN_B - 1) part[b] = buf[SCAN_B - 1];
}

__global__ __launch_bounds__(128) void scan_part_kernel(int* __restrict__ part, int* __restrict__ off,
                                                        int nb, int n) {
    __shared__ int buf[128];
    int t = threadIdx.x;
    int v = (t < nb) ? part[t] : 0;
    buf[t] = v;
    __syncthreads();
    for (int d = 1; d < 128; d <<= 1) {
        int add = (t >= d) ? buf[t - d] : 0;
        __syncthreads();
        buf[t] += add;
        __syncthreads();
    }
    if (t < nb) part[t] = buf[t] - v;
    if (t == 127) off[n] = buf[127];
}

__global__ __launch_bounds__(1024) void scan_add_kernel(int* __restrict__ off, const int* __restrict__ part,
                                                        int* __restrict__ cursor, int n) {
    int b = blockIdx.x;
    int i = b * SCAN_B + threadIdx.x;
    if (i < n) {
        int v = off[i] + part[b];
        off[i] = v;
        cursor[i] = v;
    }
}

__global__ __launch_bounds__(256) void scatter_kernel(const int* __restrict__ src, const int* __restrict__ dst,
                                                      int e, int* __restrict__ cursor, int* __restrict__ csr) {
    int i = blockIdx.x * 256 + threadIdx.x;
    if (i < e) {
        int d = dst[i];
        int pos = atomicAdd(&cursor[d], 1);
        csr[pos] = src[i];
    }
}

// ---------------- weight transpose+convert: Wt[n][k] = bf16(W[k][n]) ----------------
__global__ __launch_bounds__(128) void wt_kernel(const float* __restrict__ W, u16* __restrict__ Wt) {
    int k = blockIdx.x, n = threadIdx.x;
    Wt[n * HID + k] = bf16r(W[k * HID + n]);
}

// ---------------- f32 VALU GEMM (only for tiny zW table) ----------------
#define FMA4(acc, s, w) { acc.x += (s)*(w).x; acc.y += (s)*(w).y; acc.z += (s)*(w).z; acc.w += (s)*(w).w; }
__global__ __launch_bounds__(256) void gemm128_kernel(
    const float* __restrict__ X, const float* __restrict__ W,
    float* __restrict__ Y, int nrows)
{
    __shared__ float xs[32][132];
    int t = threadIdx.x;
    int row0 = blockIdx.x * 32;
    int sr = t >> 5;
    int sk = (t & 31) * 4;
#pragma unroll
    for (int p = 0; p < 4; ++p) {
        int r = p * 8 + sr;
        int grow = row0 + r;
        float4 v = make_float4(0.f, 0.f, 0.f, 0.f);
        if (grow < nrows) v = *(const float4*)(X + (long)grow * HID + sk);
        *(float4*)(&xs[r][sk]) = v;
    }
    __syncthreads();
    int cg = t & 31, rg = t >> 5;
    int c = cg * 4, r = rg * 4;
    float4 a0 = make_float4(0,0,0,0), a1 = a0, a2 = a0, a3 = a0;
    for (int k = 0; k < 128; k += 4) {
        float x0[4], x1[4], x2[4], x3[4];
        *(float4*)x0 = *(const float4*)&xs[r + 0][k];
        *(float4*)x1 = *(const float4*)&xs[r + 1][k];
        *(float4*)x2 = *(const float4*)&xs[r + 2][k];
        *(float4*)x3 = *(const float4*)&xs[r + 3][k];
#pragma unroll
        for (int j = 0; j < 4; ++j) {
            float4 w = *(const float4*)(W + (k + j) * HID + c);
            FMA4(a0, x0[j], w); FMA4(a1, x1[j], w); FMA4(a2, x2[j], w); FMA4(a3, x3[j], w);
        }
    }
    float4 accs[4] = {a0, a1, a2, a3};
#pragma unroll
    for (int i = 0; i < 4; ++i) {
        int grow = row0 + r + i;
        if (grow < nrows) *(float4*)(Y + (long)grow * HID + c) = accs[i];
    }
}

// ---------------- MFMA bf16 GEMM: Y = Xsrc @ W  (W pre-transposed [N][K] bf16) ----------------
// SRC_BF16=0: Xsrc f32 with optional row-gather, optional per-row f32 add-table (layer 0).
// SRC_BF16=1: Xsrc bf16 contiguous rows.
template<int SRC_BF16>
__global__ __launch_bounds__(256) void mfma_gemm_kernel(
    const void* __restrict__ Xsrc,
    const int* __restrict__ gatherIdx,
    const u16* __restrict__ Wt,
    const float* __restrict__ addTab, const int* __restrict__ addIdx,
    u16* __restrict__ Y, int nrows)
{
    __shared__ u16 Als[64][136];    // [row][k], pad 8 (16B) keeps b128 alignment
    __shared__ u16 Wls[128][136];   // [n][k]
    int t = threadIdx.x;
    int row0 = blockIdx.x * 64;

    // stage W (32KB): 2 iters, 64B per thread
#pragma unroll
    for (int p = 0; p < 2; ++p) {
        int n = p * 64 + (t >> 2);
        int k0 = (t & 3) * 32;
        const u16* src = Wt + n * HID + k0;
        uint4 v0 = *(const uint4*)(src);
        uint4 v1 = *(const uint4*)(src + 8);
        uint4 v2 = *(const uint4*)(src + 16);
        uint4 v3 = *(const uint4*)(src + 24);
        *(uint4*)&Wls[n][k0]      = v0;
        *(uint4*)&Wls[n][k0 + 8]  = v1;
        *(uint4*)&Wls[n][k0 + 16] = v2;
        *(uint4*)&Wls[n][k0 + 24] = v3;
    }

    // stage A: 64 rows x 128 k
    if (SRC_BF16) {
        const u16* X = (const u16*)Xsrc;
#pragma unroll
        for (int p = 0; p < 4; ++p) {
            int r = p * 16 + (t >> 4);
            int k0 = (t & 15) * 8;
            int grow = row0 + r;
            uint4 v = make_uint4(0, 0, 0, 0);
            if (grow < nrows) {
                long srow = gatherIdx ? (long)gatherIdx[grow] : (long)grow;
                v = *(const uint4*)(X + srow * HID + k0);
            }
            *(uint4*)&Als[r][k0] = v;
        }
    } else {
        const float* X = (const float*)Xsrc;
#pragma unroll
        for (int p = 0; p < 8; ++p) {
            int r = p * 8 + (t >> 5);
            int k0 = (t & 31) * 4;
            int grow = row0 + r;
            float4 v = make_float4(0.f, 0.f, 0.f, 0.f);
            if (grow < nrows) {
                long srow = gatherIdx ? (long)gatherIdx[grow] : (long)grow;
                v = *(const float4*)(X + srow * HID + k0);
            }
            ushort4 b;
            b.x = bf16r(v.x); b.y = bf16r(v.y); b.z = bf16r(v.z); b.w = bf16r(v.w);
            *(ushort4*)&Als[r][k0] = b;
        }
    }
    __syncthreads();

    int w = t >> 6, l = t & 63;
    int lr = l & 15, lq = l >> 4;
    f32x4 acc[8];
#pragma unroll
    for (int i = 0; i < 8; ++i) acc[i] = (f32x4){0.f, 0.f, 0.f, 0.f};

#pragma unroll
    for (int kk = 0; kk < 4; ++kk) {
        bf16x8 af = *(const bf16x8*)&Als[w * 16 + lr][kk * 32 + lq * 8];
#pragma unroll
        for (int nt = 0; nt < 8; ++nt) {
            bf16x8 bf = *(const bf16x8*)&Wls[nt * 16 + lr][kk * 32 + lq * 8];
            acc[nt] = __builtin_amdgcn_mfma_f32_16x16x32_bf16(af, bf, acc[nt], 0, 0, 0);
        }
    }

    // epilogue: C/D map col=lane&15, row=(lane>>4)*4+reg (m89-verified)
    int orow = row0 + w * 16 + lq * 4;
#pragma unroll
    for (int r = 0; r < 4; ++r) {
        int grow = orow + r;
        if (grow < nrows) {
            const float* ap = addTab ? (addTab + (long)addIdx[grow] * HID) : nullptr;
#pragma unroll
            for (int nt = 0; nt < 8; ++nt) {
                int col = nt * 16 + lr;
                float v = acc[nt][r];
                if (ap) v += ap[col];
                Y[(long)grow * HID + col] = bf16r(v);
            }
        }
    }
}

// ---------------- aggregate (bf16 H): Xo[i] = f(H[i] + sum_j H[j] + bias) ----------------
__global__ __launch_bounds__(256) void aggregate_kernel(
    const u16* __restrict__ H, u16* __restrict__ Xo,
    const int* __restrict__ off, const int* __restrict__ csr,
    const float* __restrict__ bias, int n, int doRelu)
{
    int node = blockIdx.x * 4 + (threadIdx.x >> 6);   // one wave per node
    if (node >= n) return;
    int lane = threadIdx.x & 63;
    int f = lane * 2;
    u32 u = *(const u32*)(H + (long)node * HID + f);
    float ax = bflo(u), ay = bfhi(u);
    int s = off[node], e = off[node + 1];
    for (int j = s; j < e; ++j) {
        int srcN = csr[j];
        u32 v = *(const u32*)(H + (long)srcN * HID + f);
        ax += bflo(v); ay += bfhi(v);
    }
    float2 bb = *(const float2*)(bias + f);
    ax += bb.x; ay += bb.y;
    if (doRelu) { ax = fmaxf(ax, 0.f); ay = fmaxf(ay, 0.f); }
    u32 outw = (u32)bf16r(ax) | ((u32)bf16r(ay) << 16);
    *(u32*)(Xo + (long)node * HID + f) = outw;
}

// ---------------- pooling: per-graph mean (batch sorted), bf16 in, f32 out ----------------
__global__ __launch_bounds__(128) void pool_kernel(const u16* __restrict__ X, const int* __restrict__ batch,
                                                   int n, float* __restrict__ pooled) {
    int g = blockIdx.x;
    int t = threadIdx.x;
    int lo = 0, hi = n;
    while (lo < hi) { int m = (lo + hi) >> 1; if (batch[m] < g) lo = m + 1; else hi = m; }
    int s = lo;
    lo = 0; hi = n;
    while (lo < hi) { int m = (lo + hi) >> 1; if (batch[m] < g + 1) lo = m + 1; else hi = m; }
    int e = lo;
    float acc = 0.f;
    for (int i = s; i < e; ++i) acc += __uint_as_float((u32)X[(long)i * HID + t] << 16);
    float cnt = (float)(e - s);
    pooled[g * HID + t] = acc / fmaxf(cnt, 1.f);
}

// ---------------- MLP head ----------------
__global__ __launch_bounds__(128) void mlp_kernel(
    const float* __restrict__ pooled, const float* __restrict__ W1, const float* __restrict__ b1,
    const float* __restrict__ gamma, const float* __restrict__ beta,
    const float* __restrict__ W2, const float* __restrict__ b2, float* __restrict__ out)
{
    int g = blockIdx.x, t = threadIdx.x;
    __shared__ float p[HID];
    __shared__ float red[4];
    p[t] = pooled[g * HID + t];
    __syncthreads();
    float acc = b1[t];
    for (int k = 0; k < HID; ++k) acc += p[k] * W1[k * HID + t];
    const float inv = 1.0f / sqrtf(1.0f + 1e-5f);
    acc = acc * (gamma[t] * inv) + beta[t];
    acc = fmaxf(acc, 0.f);
    float v0 = acc * W2[t * 2 + 0];
    float v1 = acc * W2[t * 2 + 1];
    for (int d = 32; d > 0; d >>= 1) { v0 += __shfl_down(v0, d); v1 += __shfl_down(v1, d); }
    int w = t >> 6, lane = t & 63;
    if (lane == 0) { red[w * 2] = v0; red[w * 2 + 1] = v1; }
    __syncthreads();
    if (t == 0) {
        out[g * 2 + 0] = red[0] + red[2] + b2[0];
        out[g * 2 + 1] = red[1] + red[3] + b2[1];
    }
}

extern "C" void kernel_launch(void* const* d_in, const int* in_sizes, int n_in,
                              void* d_out, int out_size, void* d_ws, size_t ws_size,
                              hipStream_t stream) {
    const int*   z        = (const int*)d_in[1];
    const int*   ei       = (const int*)d_in[2];
    const int*   batch    = (const int*)d_in[3];
    const int*   node_id  = (const int*)d_in[4];
    const float* z_emb    = (const float*)d_in[5];
    const float* node_emb = (const float*)d_in[6];
    const float* W0  = (const float*)d_in[7];
    const float* b0  = (const float*)d_in[8];
    const float* W1  = (const float*)d_in[9];
    const float* b1  = (const float*)d_in[10];
    const float* W2  = (const float*)d_in[11];
    const float* b2  = (const float*)d_in[12];
    const float* mW1 = (const float*)d_in[13];
    const float* mb1 = (const float*)d_in[14];
    const float* gam = (const float*)d_in[15];
    const float* bet = (const float*)d_in[16];
    const float* mW2 = (const float*)d_in[17];
    const float* mb2 = (const float*)d_in[18];
    float* out = (float*)d_out;

    const int* srcArr = ei;
    const int* dstArr = ei + NE;

    char* ws = (char*)d_ws;
    size_t o = 0;
    auto alloc = [&](size_t bytes) { char* p = ws + o; o += (bytes + 255) & ~(size_t)255; return p; };
    u16*   A      = (u16*)alloc((size_t)NN * HID * 2);     // aggregate out
    u16*   B      = (u16*)alloc((size_t)NN * HID * 2);     // gemm out (H)
    float* zW     = (float*)alloc((size_t)MAXZ * HID * 4);
    u16*   W0bt   = (u16*)alloc((size_t)HID * HID * 2);
    u16*   W1t    = (u16*)alloc((size_t)HID * HID * 2);
    u16*   W2t    = (u16*)alloc((size_t)HID * HID * 2);
    int*   deg    = (int*)alloc((size_t)NN * 4);
    int*   off    = (int*)alloc((size_t)(NN + 1) * 4);
    int*   cursor = (int*)alloc((size_t)NN * 4);
    int*   csr    = (int*)alloc((size_t)NE * 4);
    int*   part   = (int*)alloc((size_t)NBLK * 4);
    float* pooled = (float*)alloc((size_t)NG * HID * 4);
    (void)ws_size;

    // CSR by dst
    hipMemsetAsync(deg, 0, (size_t)NN * 4, stream);
    hist_kernel<<<(NE + 255) / 256, 256, 0, stream>>>(dstArr, NE, deg);
    scan_block_kernel<<<NBLK, SCAN_B, 0, stream>>>(deg, off, part, NN);
    scan_part_kernel<<<1, 128, 0, stream>>>(part, off, NBLK, NN);
    scan_add_kernel<<<NBLK, SCAN_B, 0, stream>>>(off, part, cursor, NN);
    scatter_kernel<<<(NE + 255) / 256, 256, 0, stream>>>(srcArr, dstArr, NE, cursor, csr);

    // weights: transpose+convert to bf16 [N][K]
    wt_kernel<<<HID, HID, 0, stream>>>(W0 + HID * HID, W0bt);   // bottom half of W0
    wt_kernel<<<HID, HID, 0, stream>>>(W1, W1t);
    wt_kernel<<<HID, HID, 0, stream>>>(W2, W2t);

    // zW = z_emb @ W0_top   (f32, tiny)
    gemm128_kernel<<<(MAXZ + 31) / 32, 256, 0, stream>>>(z_emb, W0, zW, MAXZ);

    const int GB = (NN + 63) / 64;
    // layer 0: B = bf16( node_emb[node_id] @ W0_bot + zW[z] )
    mfma_gemm_kernel<0><<<GB, 256, 0, stream>>>(node_emb, node_id, W0bt, zW, z, B, NN);
    aggregate_kernel<<<NN / 4, 256, 0, stream>>>(B, A, off, csr, b0, NN, 1);
    // layer 1
    mfma_gemm_kernel<1><<<GB, 256, 0, stream>>>(A, nullptr, W1t, nullptr, nullptr, B, NN);
    aggregate_kernel<<<NN / 4, 256, 0, stream>>>(B, A, off, csr, b1, NN, 1);
    // layer 2 (no relu after aggregate)
    mfma_gemm_kernel<1><<<GB, 256, 0, stream>>>(A, nullptr, W2t, nullptr, nullptr, B, NN);
    aggregate_kernel<<<NN / 4, 256, 0, stream>>>(B, A, off, csr, b2, NN, 0);

    pool_kernel<<<NG, 128, 0, stream>>>(A, batch, NN, pooled);
    mlp_kernel<<<NG, 128, 0, stream>>>(pooled, mW1, mb1, gam, bet, mW2, mb2, out);
}

// Round 4
// 565.249 us; speedup vs baseline: 1.9969x; 1.4586x over previous
//
#include <hip/hip_runtime.h>

#define NN 100000
#define NE 1600000
#define HID 128
#define NG 512
#define MAXZ 1000
#define SCAN_B 1024
#define NBLK ((NN + SCAN_B - 1) / SCAN_B)   // 98

typedef unsigned short u16;
typedef unsigned int u32;
typedef __attribute__((ext_vector_type(8))) short bf16x8;
typedef __attribute__((ext_vector_type(4))) float f32x4;

__device__ __forceinline__ u16 bf16r(float x) {     // RNE f32->bf16
    u32 u = __float_as_uint(x);
    u32 r = (u + 0x7fffu + ((u >> 16) & 1u)) >> 16;
    return (u16)r;
}
__device__ __forceinline__ float bflo(u32 u) { return __uint_as_float(u << 16); }
__device__ __forceinline__ float bfhi(u32 u) { return __uint_as_float(u & 0xffff0000u); }

// ---------------- CSR build ----------------
__global__ __launch_bounds__(256) void hist_kernel(const int* __restrict__ dst, int e, int* __restrict__ deg) {
    int i = blockIdx.x * 256 + threadIdx.x;
    if (i < e) atomicAdd(&deg[dst[i]], 1);
}

__global__ __launch_bounds__(1024) void scan_block_kernel(const int* __restrict__ deg, int* __restrict__ off,
                                                          int* __restrict__ part, int n) {
    __shared__ int buf[SCAN_B];
    int b = blockIdx.x, t = threadIdx.x;
    int i = b * SCAN_B + t;
    int v = (i < n) ? deg[i] : 0;
    buf[t] = v;
    __syncthreads();
    for (int d = 1; d < SCAN_B; d <<= 1) {
        int add = (t >= d) ? buf[t - d] : 0;
        __syncthreads();
        buf[t] += add;
        __syncthreads();
    }
    if (i < n) off[i] = buf[t] - v;
    if (t == SCAN_B - 1) part[b] = buf[SCAN_B - 1];
}

__global__ __launch_bounds__(128) void scan_part_kernel(int* __restrict__ part, int* __restrict__ off,
                                                        int nb, int n) {
    __shared__ int buf[128];
    int t = threadIdx.x;
    int v = (t < nb) ? part[t] : 0;
    buf[t] = v;
    __syncthreads();
    for (int d = 1; d < 128; d <<= 1) {
        int add = (t >= d) ? buf[t - d] : 0;
        __syncthreads();
        buf[t] += add;
        __syncthreads();
    }
    if (t < nb) part[t] = buf[t] - v;
    if (t == 127) off[n] = buf[127];
}

__global__ __launch_bounds__(1024) void scan_add_kernel(int* __restrict__ off, const int* __restrict__ part,
                                                        int* __restrict__ cursor, int n) {
    int b = blockIdx.x;
    int i = b * SCAN_B + threadIdx.x;
    if (i < n) {
        int v = off[i] + part[b];
        off[i] = v;
        cursor[i] = v;
    }
}

__global__ __launch_bounds__(256) void scatter_kernel(const int* __restrict__ src, const int* __restrict__ dst,
                                                      int e, int* __restrict__ cursor, int* __restrict__ csr) {
    int i = blockIdx.x * 256 + threadIdx.x;
    if (i < e) {
        int d = dst[i];
        int pos = atomicAdd(&cursor[d], 1);
        csr[pos] = src[i];
    }
}

// ---------------- weight transpose+convert: Wt[n][k] = bf16(W[k][n]) ----------------
__global__ __launch_bounds__(128) void wt_kernel(const float* __restrict__ W, u16* __restrict__ Wt) {
    int k = blockIdx.x, n = threadIdx.x;
    Wt[n * HID + k] = bf16r(W[k * HID + n]);
}

// ---------------- f32 VALU GEMM (only for tiny zW table) ----------------
#define FMA4(acc, s, w) { acc.x += (s)*(w).x; acc.y += (s)*(w).y; acc.z += (s)*(w).z; acc.w += (s)*(w).w; }
__global__ __launch_bounds__(256) void gemm128_kernel(
    const float* __restrict__ X, const float* __restrict__ W,
    float* __restrict__ Y, int nrows)
{
    __shared__ float xs[32][132];
    int t = threadIdx.x;
    int row0 = blockIdx.x * 32;
    int sr = t >> 5;
    int sk = (t & 31) * 4;
#pragma unroll
    for (int p = 0; p < 4; ++p) {
        int r = p * 8 + sr;
        int grow = row0 + r;
        float4 v = make_float4(0.f, 0.f, 0.f, 0.f);
        if (grow < nrows) v = *(const float4*)(X + (long)grow * HID + sk);
        *(float4*)(&xs[r][sk]) = v;
    }
    __syncthreads();
    int cg = t & 31, rg = t >> 5;
    int c = cg * 4, r = rg * 4;
    float4 a0 = make_float4(0,0,0,0), a1 = a0, a2 = a0, a3 = a0;
    for (int k = 0; k < 128; k += 4) {
        float x0[4], x1[4], x2[4], x3[4];
        *(float4*)x0 = *(const float4*)&xs[r + 0][k];
        *(float4*)x1 = *(const float4*)&xs[r + 1][k];
        *(float4*)x2 = *(const float4*)&xs[r + 2][k];
        *(float4*)x3 = *(const float4*)&xs[r + 3][k];
#pragma unroll
        for (int j = 0; j < 4; ++j) {
            float4 w = *(const float4*)(W + (k + j) * HID + c);
            FMA4(a0, x0[j], w); FMA4(a1, x1[j], w); FMA4(a2, x2[j], w); FMA4(a3, x3[j], w);
        }
    }
    float4 accs[4] = {a0, a1, a2, a3};
#pragma unroll
    for (int i = 0; i < 4; ++i) {
        int grow = row0 + r + i;
        if (grow < nrows) *(float4*)(Y + (long)grow * HID + c) = accs[i];
    }
}

// ---------------- MFMA bf16 GEMM: Y = Xsrc @ W  (W pre-transposed [N][K] bf16) ----------------
template<int SRC_BF16>
__global__ __launch_bounds__(256) void mfma_gemm_kernel(
    const void* __restrict__ Xsrc,
    const int* __restrict__ gatherIdx,
    const u16* __restrict__ Wt,
    const float* __restrict__ addTab, const int* __restrict__ addIdx,
    u16* __restrict__ Y, int nrows)
{
    __shared__ u16 Als[64][136];
    __shared__ u16 Wls[128][136];
    int t = threadIdx.x;
    int row0 = blockIdx.x * 64;

#pragma unroll
    for (int p = 0; p < 2; ++p) {
        int n = p * 64 + (t >> 2);
        int k0 = (t & 3) * 32;
        const u16* src = Wt + n * HID + k0;
        uint4 v0 = *(const uint4*)(src);
        uint4 v1 = *(const uint4*)(src + 8);
        uint4 v2 = *(const uint4*)(src + 16);
        uint4 v3 = *(const uint4*)(src + 24);
        *(uint4*)&Wls[n][k0]      = v0;
        *(uint4*)&Wls[n][k0 + 8]  = v1;
        *(uint4*)&Wls[n][k0 + 16] = v2;
        *(uint4*)&Wls[n][k0 + 24] = v3;
    }

    if (SRC_BF16) {
        const u16* X = (const u16*)Xsrc;
#pragma unroll
        for (int p = 0; p < 4; ++p) {
            int r = p * 16 + (t >> 4);
            int k0 = (t & 15) * 8;
            int grow = row0 + r;
            uint4 v = make_uint4(0, 0, 0, 0);
            if (grow < nrows) {
                long srow = gatherIdx ? (long)gatherIdx[grow] : (long)grow;
                v = *(const uint4*)(X + srow * HID + k0);
            }
            *(uint4*)&Als[r][k0] = v;
        }
    } else {
        const float* X = (const float*)Xsrc;
#pragma unroll
        for (int p = 0; p < 8; ++p) {
            int r = p * 8 + (t >> 5);
            int k0 = (t & 31) * 4;
            int grow = row0 + r;
            float4 v = make_float4(0.f, 0.f, 0.f, 0.f);
            if (grow < nrows) {
                long srow = gatherIdx ? (long)gatherIdx[grow] : (long)grow;
                v = *(const float4*)(X + srow * HID + k0);
            }
            ushort4 b;
            b.x = bf16r(v.x); b.y = bf16r(v.y); b.z = bf16r(v.z); b.w = bf16r(v.w);
            *(ushort4*)&Als[r][k0] = b;
        }
    }
    __syncthreads();

    int w = t >> 6, l = t & 63;
    int lr = l & 15, lq = l >> 4;
    f32x4 acc[8];
#pragma unroll
    for (int i = 0; i < 8; ++i) acc[i] = (f32x4){0.f, 0.f, 0.f, 0.f};

#pragma unroll
    for (int kk = 0; kk < 4; ++kk) {
        bf16x8 af = *(const bf16x8*)&Als[w * 16 + lr][kk * 32 + lq * 8];
#pragma unroll
        for (int nt = 0; nt < 8; ++nt) {
            bf16x8 bf = *(const bf16x8*)&Wls[nt * 16 + lr][kk * 32 + lq * 8];
            acc[nt] = __builtin_amdgcn_mfma_f32_16x16x32_bf16(af, bf, acc[nt], 0, 0, 0);
        }
    }

    int orow = row0 + w * 16 + lq * 4;
#pragma unroll
    for (int r = 0; r < 4; ++r) {
        int grow = orow + r;
        if (grow < nrows) {
            const float* ap = addTab ? (addTab + (long)addIdx[grow] * HID) : nullptr;
#pragma unroll
            for (int nt = 0; nt < 8; ++nt) {
                int col = nt * 16 + lr;
                float v = acc[nt][r];
                if (ap) v += ap[col];
                Y[(long)grow * HID + col] = bf16r(v);
            }
        }
    }
}

// ---------------- aggregate (bf16 H), latency-optimized ----------------
// One wave per node. 16 lanes cover a 256B row (uint4 = 8 bf16 each); the 4
// lane-groups process 4 edges per iteration. Indices prefetched; 2 row-loads
// in flight. Cross-group combine via shfl_xor(16|32).
__global__ __launch_bounds__(256) void aggregate_kernel(
    const u16* __restrict__ H, u16* __restrict__ Xo,
    const int* __restrict__ off, const int* __restrict__ csr,
    const float* __restrict__ bias, int n, int doRelu)
{
    int node = blockIdx.x * 4 + (threadIdx.x >> 6);
    if (node >= n) return;
    int lane = threadIdx.x & 63;
    int g = lane >> 4, fl = lane & 15;
    int s = off[node], e = off[node + 1];

    float acc[8] = {0.f, 0.f, 0.f, 0.f, 0.f, 0.f, 0.f, 0.f};
    int j = s + g;

    // 2-deep: edges j and j+4 per step
    for (; j + 4 < e; j += 8) {
        int i0 = csr[j];
        int i1 = csr[j + 4];
        uint4 v0 = *(const uint4*)(H + (long)i0 * HID + fl * 8);
        uint4 v1 = *(const uint4*)(H + (long)i1 * HID + fl * 8);
        acc[0] += bflo(v0.x); acc[1] += bfhi(v0.x);
        acc[2] += bflo(v0.y); acc[3] += bfhi(v0.y);
        acc[4] += bflo(v0.z); acc[5] += bfhi(v0.z);
        acc[6] += bflo(v0.w); acc[7] += bfhi(v0.w);
        acc[0] += bflo(v1.x); acc[1] += bfhi(v1.x);
        acc[2] += bflo(v1.y); acc[3] += bfhi(v1.y);
        acc[4] += bflo(v1.z); acc[5] += bfhi(v1.z);
        acc[6] += bflo(v1.w); acc[7] += bfhi(v1.w);
    }
    if (j < e) {
        int i0 = csr[j];
        uint4 v0 = *(const uint4*)(H + (long)i0 * HID + fl * 8);
        acc[0] += bflo(v0.x); acc[1] += bfhi(v0.x);
        acc[2] += bflo(v0.y); acc[3] += bfhi(v0.y);
        acc[4] += bflo(v0.z); acc[5] += bfhi(v0.z);
        acc[6] += bflo(v0.w); acc[7] += bfhi(v0.w);
    }

#pragma unroll
    for (int i = 0; i < 8; ++i) {
        acc[i] += __shfl_xor(acc[i], 16);
        acc[i] += __shfl_xor(acc[i], 32);
    }

    if (g == 0) {
        uint4 sv = *(const uint4*)(H + (long)node * HID + fl * 8);   // self (eps=0)
        float4 ba = *(const float4*)(bias + fl * 8);
        float4 bb = *(const float4*)(bias + fl * 8 + 4);
        float r[8];
        r[0] = acc[0] + bflo(sv.x) + ba.x;
        r[1] = acc[1] + bfhi(sv.x) + ba.y;
        r[2] = acc[2] + bflo(sv.y) + ba.z;
        r[3] = acc[3] + bfhi(sv.y) + ba.w;
        r[4] = acc[4] + bflo(sv.z) + bb.x;
        r[5] = acc[5] + bfhi(sv.z) + bb.y;
        r[6] = acc[6] + bflo(sv.w) + bb.z;
        r[7] = acc[7] + bfhi(sv.w) + bb.w;
        if (doRelu) {
#pragma unroll
            for (int i = 0; i < 8; ++i) r[i] = fmaxf(r[i], 0.f);
        }
        uint4 ov;
        ov.x = (u32)bf16r(r[0]) | ((u32)bf16r(r[1]) << 16);
        ov.y = (u32)bf16r(r[2]) | ((u32)bf16r(r[3]) << 16);
        ov.z = (u32)bf16r(r[4]) | ((u32)bf16r(r[5]) << 16);
        ov.w = (u32)bf16r(r[6]) | ((u32)bf16r(r[7]) << 16);
        *(uint4*)(Xo + (long)node * HID + fl * 8) = ov;
    }
}

// ---------------- pooling: per-graph mean (batch sorted), bf16 in, f32 out ----------------
__global__ __launch_bounds__(128) void pool_kernel(const u16* __restrict__ X, const int* __restrict__ batch,
                                                   int n, float* __restrict__ pooled) {
    int g = blockIdx.x;
    int t = threadIdx.x;
    int lo = 0, hi = n;
    while (lo < hi) { int m = (lo + hi) >> 1; if (batch[m] < g) lo = m + 1; else hi = m; }
    int s = lo;
    lo = 0; hi = n;
    while (lo < hi) { int m = (lo + hi) >> 1; if (batch[m] < g + 1) lo = m + 1; else hi = m; }
    int e = lo;
    float acc = 0.f;
    for (int i = s; i < e; ++i) acc += __uint_as_float((u32)X[(long)i * HID + t] << 16);
    float cnt = (float)(e - s);
    pooled[g * HID + t] = acc / fmaxf(cnt, 1.f);
}

// ---------------- MLP head ----------------
__global__ __launch_bounds__(128) void mlp_kernel(
    const float* __restrict__ pooled, const float* __restrict__ W1, const float* __restrict__ b1,
    const float* __restrict__ gamma, const float* __restrict__ beta,
    const float* __restrict__ W2, const float* __restrict__ b2, float* __restrict__ out)
{
    int g = blockIdx.x, t = threadIdx.x;
    __shared__ float p[HID];
    __shared__ float red[4];
    p[t] = pooled[g * HID + t];
    __syncthreads();
    float acc = b1[t];
    for (int k = 0; k < HID; ++k) acc += p[k] * W1[k * HID + t];
    const float inv = 1.0f / sqrtf(1.0f + 1e-5f);
    acc = acc * (gamma[t] * inv) + beta[t];
    acc = fmaxf(acc, 0.f);
    float v0 = acc * W2[t * 2 + 0];
    float v1 = acc * W2[t * 2 + 1];
    for (int d = 32; d > 0; d >>= 1) { v0 += __shfl_down(v0, d); v1 += __shfl_down(v1, d); }
    int w = t >> 6, lane = t & 63;
    if (lane == 0) { red[w * 2] = v0; red[w * 2 + 1] = v1; }
    __syncthreads();
    if (t == 0) {
        out[g * 2 + 0] = red[0] + red[2] + b2[0];
        out[g * 2 + 1] = red[1] + red[3] + b2[1];
    }
}

extern "C" void kernel_launch(void* const* d_in, const int* in_sizes, int n_in,
                              void* d_out, int out_size, void* d_ws, size_t ws_size,
                              hipStream_t stream) {
    const int*   z        = (const int*)d_in[1];
    const int*   ei       = (const int*)d_in[2];
    const int*   batch    = (const int*)d_in[3];
    const int*   node_id  = (const int*)d_in[4];
    const float* z_emb    = (const float*)d_in[5];
    const float* node_emb = (const float*)d_in[6];
    const float* W0  = (const float*)d_in[7];
    const float* b0  = (const float*)d_in[8];
    const float* W1  = (const float*)d_in[9];
    const float* b1  = (const float*)d_in[10];
    const float* W2  = (const float*)d_in[11];
    const float* b2  = (const float*)d_in[12];
    const float* mW1 = (const float*)d_in[13];
    const float* mb1 = (const float*)d_in[14];
    const float* gam = (const float*)d_in[15];
    const float* bet = (const float*)d_in[16];
    const float* mW2 = (const float*)d_in[17];
    const float* mb2 = (const float*)d_in[18];
    float* out = (float*)d_out;

    const int* srcArr = ei;
    const int* dstArr = ei + NE;

    char* ws = (char*)d_ws;
    size_t o = 0;
    auto alloc = [&](size_t bytes) { char* p = ws + o; o += (bytes + 255) & ~(size_t)255; return p; };
    u16*   A      = (u16*)alloc((size_t)NN * HID * 2);
    u16*   B      = (u16*)alloc((size_t)NN * HID * 2);
    float* zW     = (float*)alloc((size_t)MAXZ * HID * 4);
    u16*   W0bt   = (u16*)alloc((size_t)HID * HID * 2);
    u16*   W1t    = (u16*)alloc((size_t)HID * HID * 2);
    u16*   W2t    = (u16*)alloc((size_t)HID * HID * 2);
    int*   deg    = (int*)alloc((size_t)NN * 4);
    int*   off    = (int*)alloc((size_t)(NN + 1) * 4);
    int*   cursor = (int*)alloc((size_t)NN * 4);
    int*   csr    = (int*)alloc((size_t)NE * 4);
    int*   part   = (int*)alloc((size_t)NBLK * 4);
    float* pooled = (float*)alloc((size_t)NG * HID * 4);
    (void)ws_size;

    // CSR by dst
    hipMemsetAsync(deg, 0, (size_t)NN * 4, stream);
    hist_kernel<<<(NE + 255) / 256, 256, 0, stream>>>(dstArr, NE, deg);
    scan_block_kernel<<<NBLK, SCAN_B, 0, stream>>>(deg, off, part, NN);
    scan_part_kernel<<<1, 128, 0, stream>>>(part, off, NBLK, NN);
    scan_add_kernel<<<NBLK, SCAN_B, 0, stream>>>(off, part, cursor, NN);
    scatter_kernel<<<(NE + 255) / 256, 256, 0, stream>>>(srcArr, dstArr, NE, cursor, csr);

    // weights
    wt_kernel<<<HID, HID, 0, stream>>>(W0 + HID * HID, W0bt);
    wt_kernel<<<HID, HID, 0, stream>>>(W1, W1t);
    wt_kernel<<<HID, HID, 0, stream>>>(W2, W2t);

    // zW = z_emb @ W0_top   (f32, tiny)
    gemm128_kernel<<<(MAXZ + 31) / 32, 256, 0, stream>>>(z_emb, W0, zW, MAXZ);

    const int GB = (NN + 63) / 64;
    mfma_gemm_kernel<0><<<GB, 256, 0, stream>>>(node_emb, node_id, W0bt, zW, z, B, NN);
    aggregate_kernel<<<NN / 4, 256, 0, stream>>>(B, A, off, csr, b0, NN, 1);
    mfma_gemm_kernel<1><<<GB, 256, 0, stream>>>(A, nullptr, W1t, nullptr, nullptr, B, NN);
    aggregate_kernel<<<NN / 4, 256, 0, stream>>>(B, A, off, csr, b1, NN, 1);
    mfma_gemm_kernel<1><<<GB, 256, 0, stream>>>(A, nullptr, W2t, nullptr, nullptr, B, NN);
    aggregate_kernel<<<NN / 4, 256, 0, stream>>>(B, A, off, csr, b2, NN, 0);

    pool_kernel<<<NG, 128, 0, stream>>>(A, batch, NN, pooled);
    mlp_kernel<<<NG, 128, 0, stream>>>(pooled, mW1, mb1, gam, bet, mW2, mb2, out);
}